// Round 12
// baseline (732.887 us; speedup 1.0000x reference)
//
#include <hip/hip_runtime.h>
#include <math.h>

#define N_NODES 15000
#define NPAD    15104      // 118*128
#define E_EDGES 240000
#define IN_DIM  100
#define HID     128
#define N_ETYPES 13
#define N_STEPS  6
#define N_GRAPHS 64
#define N_CLASSES 10
#define NTS     (N_ETYPES * NPAD)   // 196352 (d,t) cells
#define NSB     384                 // scan blocks of 512

typedef short v8bf __attribute__((ext_vector_type(8)));
typedef float v4f  __attribute__((ext_vector_type(4)));

union FragU { uint4 u; v8bf b; };

static __device__ __forceinline__ float bf2f(unsigned short u) {
    union { unsigned int i; float f; } x; x.i = ((unsigned int)u) << 16; return x.f;
}
static __device__ __forceinline__ unsigned short f2bf(float f) {
    union { float f; unsigned int i; } x; x.f = f;
    unsigned int u = x.i;
    u = (u + 0x7fff + ((u >> 16) & 1)) >> 16;   // round-nearest-even
    return (unsigned short)u;
}
static __device__ __forceinline__ float sigm(float x) { return 1.f / (1.f + expf(-x)); }

// ---------------- merged one-time init: h planes + weight frag planes (hi only) ----------------
__global__ __launch_bounds__(256) void k_initW(
    const float* __restrict__ feat,
    const float* __restrict__ W_e, const float* __restrict__ W_ih, const float* __restrict__ W_hh,
    float* __restrict__ h32, unsigned short* __restrict__ h_hi, unsigned short* __restrict__ h_lo,
    unsigned short* __restrict__ WeH,
    unsigned short* __restrict__ WihH, unsigned short* __restrict__ WhhH)
{
    int idx = blockIdx.x * 256 + threadIdx.x;
    const int IH = NPAD * HID;
    const int NE = N_ETYPES * 2048;
    const int NG = 16 * 384;
    if (idx < IH) {
        int n = idx >> 7, c = idx & 127;
        float v = 0.f;
        if (n < N_NODES && c < IN_DIM) v = feat[n * IN_DIM + c];
        h32[idx] = v;
        unsigned short hi = f2bf(v);
        h_hi[idx] = hi;
        h_lo[idx] = f2bf(v - bf2f(hi));
        return;
    }
    int f = idx - IH;
    unsigned short th[8];
    if (f < NE) {
        int t = f >> 11, r = f & 2047, kcsub = r >> 7, c = r & 127;
        #pragma unroll
        for (int j = 0; j < 8; ++j)
            th[j] = f2bf(W_e[(long)t * 16384 + (kcsub * 8 + j) * 128 + c]);
        *(uint4*)(WeH + (long)t * 16384 + ((kcsub << 7) + c) * 8) = *(uint4*)th;
    } else if (f < NE + 2 * NG) {
        int f2 = f - NE;
        const float* srcp = (f2 < NG) ? W_ih : W_hh;
        unsigned short* dh = (f2 < NG) ? WihH : WhhH;
        int g = (f2 < NG) ? f2 : f2 - NG;
        int kcsub = g / 384, c = g - kcsub * 384;
        #pragma unroll
        for (int j = 0; j < 8; ++j)
            th[j] = f2bf(srcp[(long)c * 128 + kcsub * 8 + j]);   // B[k][c] = W[c][k]
        *(uint4*)(dh + ((long)kcsub * 384 + c) * 8) = *(uint4*)th;
    }
}

__global__ __launch_bounds__(256) void k_zeroi(int* __restrict__ p, int n) {
    int idx = blockIdx.x * 256 + threadIdx.x;
    if (idx < n) p[idx] = 0;
}

// ---------------- (dst,etype) CSR build ----------------
__global__ __launch_bounds__(256) void k_countDT(const int* __restrict__ dst,
                                                 const int* __restrict__ et,
                                                 int* __restrict__ cnt) {
    int e = blockIdx.x * 256 + threadIdx.x;
    if (e >= E_EDGES) return;
    atomicAdd(&cnt[dst[e] * N_ETYPES + et[e]], 1);
}

__global__ __launch_bounds__(512) void k_su1(const int* __restrict__ cnt, int* __restrict__ bsum) {
    __shared__ int sh[512];
    int tid = threadIdx.x;
    int i = blockIdx.x * 512 + tid;
    sh[tid] = (i < NTS) ? cnt[i] : 0;
    __syncthreads();
    for (int off = 256; off > 0; off >>= 1) {
        if (tid < off) sh[tid] += sh[tid + off];
        __syncthreads();
    }
    if (tid == 0) bsum[blockIdx.x] = sh[0];
}

__global__ __launch_bounds__(512) void k_su2(const int* __restrict__ bsum, int* __restrict__ bofs) {
    __shared__ int sh[512];
    int tid = threadIdx.x;
    int v = (tid < NSB) ? bsum[tid] : 0;
    sh[tid] = v; __syncthreads();
    for (int off = 1; off < 512; off <<= 1) {
        int u = (tid >= off) ? sh[tid - off] : 0;
        __syncthreads();
        sh[tid] += u;
        __syncthreads();
    }
    if (tid < NSB) bofs[tid] = sh[tid] - v;   // exclusive
}

__global__ __launch_bounds__(512) void k_su3(const int* __restrict__ cnt,
                                             const int* __restrict__ bofs,
                                             int* __restrict__ rowptrDT,
                                             int* __restrict__ cursorDT) {
    __shared__ int sh[512];
    int tid = threadIdx.x;
    int i = blockIdx.x * 512 + tid;
    int f = (i < NTS) ? cnt[i] : 0;
    sh[tid] = f; __syncthreads();
    for (int off = 1; off < 512; off <<= 1) {
        int u = (tid >= off) ? sh[tid - off] : 0;
        __syncthreads();
        sh[tid] += u;
        __syncthreads();
    }
    int g = bofs[blockIdx.x] + sh[tid] - f;   // global exclusive prefix
    if (i <= NTS) {
        rowptrDT[i] = g;
        if (i < NTS) cursorDT[i] = g;
    }
}

__global__ __launch_bounds__(256) void k_fillDT(const int* __restrict__ src,
                                                const int* __restrict__ dst,
                                                const int* __restrict__ et,
                                                int* __restrict__ cursorDT,
                                                int* __restrict__ epay) {
    int e = blockIdx.x * 256 + threadIdx.x;
    if (e >= E_EDGES) return;
    int pos = atomicAdd(&cursorDT[dst[e] * N_ETYPES + et[e]], 1);
    epay[pos] = src[e];
}

// prebias[d][c] = sum_t cnt(d,t) * b_e[t][c]
__global__ __launch_bounds__(256) void k_prebias(const int* __restrict__ rowptrDT,
                                                 const float* __restrict__ b_e,
                                                 float* __restrict__ prebias) {
    int idx = blockIdx.x * 256 + threadIdx.x;
    if (idx >= NPAD * HID) return;
    int d = idx >> 7, c = idx & 127;
    const int* rp = rowptrDT + d * N_ETYPES;
    float s = 0.f;
    int prev = rp[0];
    #pragma unroll
    for (int t = 0; t < N_ETYPES; ++t) {
        int nxt = rp[t + 1];
        s += (float)(nxt - prev) * b_e[t * 128 + c];
        prev = nxt;
    }
    prebias[idx] = s;
}

// ---------------- fused gather + etype GEMM: a = sum_t (sum_{e in t} h[src]) @ W_t + prebias ----
// grid (118, 2): 128 dst rows x 64-col half. 512 thr = 8 waves; wave owns 16 rows.
// lane (r = lane&15, ksub = lane>>4): gathers row r, k-cols ksub*32..+32 in fp32 regs.
// Wave-private LDS tile (hi/lo bf16, XOR-swizzled), no atomics, no barriers.
__global__ __launch_bounds__(512) void k_fuse(
    const float* __restrict__ h32r,
    const int* __restrict__ rowptrDT, const int* __restrict__ epay,
    const uint4* __restrict__ WeH,
    const float* __restrict__ prebias,
    unsigned short* __restrict__ a_hi)
{
    __shared__ char lds[8 * 8192];          // 64 KB: 8 KB per wave (hi 4K + lo 4K)
    int tid = threadIdx.x, lane = tid & 63, w = tid >> 6;
    int ch = blockIdx.y;
    int r = lane & 15, ksub = lane >> 4;
    int d0 = blockIdx.x * 128 + w * 16;
    int d = d0 + r;
    char* wl = lds + w * 8192;

    v4f acc[4];
    #pragma unroll
    for (int c8 = 0; c8 < 4; ++c8) acc[c8] = (v4f)(0.f);

    int rpv[N_ETYPES + 1];
    {
        const int* rp = rowptrDT + d * N_ETYPES;
        #pragma unroll
        for (int t = 0; t <= N_ETYPES; ++t) rpv[t] = rp[t];
    }

    for (int t = 0; t < N_ETYPES; ++t) {
        int s = rpv[t], e = rpv[t + 1];
        if (__all(s == e)) continue;
        float g[32];
        #pragma unroll
        for (int q = 0; q < 32; ++q) g[q] = 0.f;
        const float4* hb = (const float4*)h32r;
        for (int i = s; i < e; ++i) {
            int srcn = epay[i];
            const float4* hrow = hb + srcn * 32 + ksub * 8;
            #pragma unroll
            for (int jj = 0; jj < 8; ++jj) {
                float4 v = hrow[jj];
                g[jj * 4 + 0] += v.x;
                g[jj * 4 + 1] += v.y;
                g[jj * 4 + 2] += v.z;
                g[jj * 4 + 3] += v.w;
            }
        }
        // fp32 -> bf16 hi/lo, wave-private swizzled LDS
        #pragma unroll
        for (int j = 0; j < 4; ++j) {
            unsigned int hw[4], lw[4];
            #pragma unroll
            for (int p = 0; p < 4; ++p) {
                float v0 = g[j * 8 + 2 * p], v1 = g[j * 8 + 2 * p + 1];
                unsigned short h0 = f2bf(v0), h1 = f2bf(v1);
                hw[p] = (unsigned int)h0 | ((unsigned int)h1 << 16);
                lw[p] = (unsigned int)f2bf(v0 - bf2f(h0)) |
                        ((unsigned int)f2bf(v1 - bf2f(h1)) << 16);
            }
            int byt = (r * 256 + ksub * 64 + j * 16) ^ ((r & 7) << 4);
            *(uint4*)(wl + byt) = make_uint4(hw[0], hw[1], hw[2], hw[3]);
            *(uint4*)(wl + 4096 + byt) = make_uint4(lw[0], lw[1], lw[2], lw[3]);
        }
        // A-frags (lane: row=r, k-chunk=ksub) + MFMA vs W_t (L2-hot)
        #pragma unroll
        for (int kc = 0; kc < 4; ++kc) {
            int byt = (r * 256 + kc * 64 + ksub * 16) ^ ((r & 7) << 4);
            FragU ah, al;
            ah.u = *(const uint4*)(wl + byt);
            al.u = *(const uint4*)(wl + 4096 + byt);
            #pragma unroll
            for (int c8 = 0; c8 < 4; ++c8) {
                int bi = (kc * 4 + ksub) * 128 + ch * 64 + c8 * 16 + r;
                FragU bf_; bf_.u = WeH[t * 2048 + bi];
                acc[c8] = __builtin_amdgcn_mfma_f32_16x16x32_bf16(ah.b, bf_.b, acc[c8], 0, 0, 0);
                acc[c8] = __builtin_amdgcn_mfma_f32_16x16x32_bf16(al.b, bf_.b, acc[c8], 0, 0, 0);
            }
        }
    }

    // epilogue: + prebias, write a_hi. C/D: col = lane&15, row = (lane>>4)*4 + i
    #pragma unroll
    for (int c8 = 0; c8 < 4; ++c8) {
        int col = ch * 64 + c8 * 16 + r;
        #pragma unroll
        for (int i = 0; i < 4; ++i) {
            int row = d0 + ksub * 4 + i;
            long off = (long)row * 128 + col;
            a_hi[off] = f2bf(acc[c8][i] + prebias[off]);
        }
    }
}

// ---------------- fused GRU: GI 1-pass, GH 2-pass ----------------
// wave = 16 rows x 16 cols; block = 16 rows x 128 cols; grid = NPAD/16.
__global__ __launch_bounds__(512) void k_gru(
    const unsigned short* __restrict__ a_hi,
    const uint4* __restrict__ WihH, const uint4* __restrict__ WhhH,
    const float* __restrict__ b_ih, const float* __restrict__ b_hh,
    float* __restrict__ h32,
    unsigned short* __restrict__ h_hi, unsigned short* __restrict__ h_lo)
{
    int tid = threadIdx.x, lane = tid & 63, cg = tid >> 6;   // cg = wave = col group
    int r0 = blockIdx.x * 16;
    int l15 = lane & 15, lsub = lane >> 4;

    FragU aa[4], hh[2][4];
    {
        const char* ahb = (const char*)a_hi;
        const char* hhb = (const char*)h_hi;
        const char* hlb = (const char*)h_lo;
        #pragma unroll
        for (int kc = 0; kc < 4; ++kc) {
            long boff = (long)(r0 + l15) * 256 + kc * 64 + lsub * 16;
            aa[kc].u    = *(const uint4*)(ahb + boff);
            hh[0][kc].u = *(const uint4*)(hhb + boff);
            hh[1][kc].u = *(const uint4*)(hlb + boff);
        }
    }
    __syncthreads();   // all waves read these h rows before any in-place writes

    v4f accI[3], accH[3];
    #pragma unroll
    for (int g = 0; g < 3; ++g) { accI[g] = (v4f)(0.f); accH[g] = (v4f)(0.f); }

    #pragma unroll
    for (int kc = 0; kc < 4; ++kc)
        #pragma unroll
        for (int g = 0; g < 3; ++g) {
            int bi = (kc * 4 + lsub) * 384 + g * 128 + cg * 16 + l15;
            FragU wih, whh;
            wih.u = WihH[bi]; whh.u = WhhH[bi];
            accI[g] = __builtin_amdgcn_mfma_f32_16x16x32_bf16(aa[kc].b,    wih.b, accI[g], 0, 0, 0);
            accH[g] = __builtin_amdgcn_mfma_f32_16x16x32_bf16(hh[0][kc].b, whh.b, accH[g], 0, 0, 0);
            accH[g] = __builtin_amdgcn_mfma_f32_16x16x32_bf16(hh[1][kc].b, whh.b, accH[g], 0, 0, 0);
        }

    int c = cg * 16 + l15;
    float bir = b_ih[c], biz = b_ih[c + 128], bin = b_ih[c + 256];
    float bhr = b_hh[c], bhz = b_hh[c + 128], bhn = b_hh[c + 256];
    #pragma unroll
    for (int i = 0; i < 4; ++i) {
        int row = r0 + lsub * 4 + i;
        float ir = accI[0][i] + bir, iz = accI[1][i] + biz, inn = accI[2][i] + bin;
        float hr = accH[0][i] + bhr, hz = accH[1][i] + bhz, hn = accH[2][i] + bhn;
        float rr = sigm(ir + hr);
        float zg = sigm(iz + hz);
        float ng = tanhf(inn + rr * hn);
        long off = (long)row * 128 + c;
        float ho = h32[off];
        float hv = (1.f - zg) * ng + zg * ho;
        if (row < N_NODES) {
            h32[off] = hv;
            unsigned short hi_ = f2bf(hv);
            h_hi[off] = hi_;
            h_lo[off] = f2bf(hv - bf2f(hi_));
        }
    }
}

// ---------------- pooling + classifier ----------------
__global__ __launch_bounds__(256) void k_pool(const float* __restrict__ h32,
                                              const int* __restrict__ gid,
                                              float* __restrict__ hg) {
    int idx = blockIdx.x * 256 + threadIdx.x;
    if (idx >= N_NODES * HID) return;
    int n = idx >> 7, c = idx & 127;
    atomicAdd(&hg[gid[n] * HID + c], h32[idx]);
}

__global__ __launch_bounds__(256) void k_zero(float* __restrict__ p, long n4) {
    long i = (long)blockIdx.x * 256 + threadIdx.x;
    if (i < n4) ((float4*)p)[i] = make_float4(0.f, 0.f, 0.f, 0.f);
}

__global__ __launch_bounds__(640) void k_cls(const float* __restrict__ hg,
                                             const float* __restrict__ Wc,
                                             const float* __restrict__ bc,
                                             float* __restrict__ out) {
    int tid = threadIdx.x;
    if (tid >= N_GRAPHS * N_CLASSES) return;
    int g = tid / N_CLASSES, c = tid - g * N_CLASSES;
    float s = bc[c];
    for (int k = 0; k < HID; ++k) s = fmaf(hg[g * HID + k], Wc[c * HID + k], s);
    out[tid] = s;
}

// ---------------- launch ----------------
extern "C" void kernel_launch(void* const* d_in, const int* in_sizes, int n_in,
                              void* d_out, int out_size, void* d_ws, size_t ws_size,
                              hipStream_t stream) {
    const float* feat  = (const float*)d_in[0];
    const int*   src   = (const int*)d_in[1];
    const int*   dst   = (const int*)d_in[2];
    const int*   et    = (const int*)d_in[3];
    const int*   gid   = (const int*)d_in[4];
    const float* W_e   = (const float*)d_in[5];
    const float* b_e   = (const float*)d_in[6];
    const float* W_ih  = (const float*)d_in[7];
    const float* W_hh  = (const float*)d_in[8];
    const float* b_ih  = (const float*)d_in[9];
    const float* b_hh  = (const float*)d_in[10];
    const float* W_cls = (const float*)d_in[11];
    const float* b_cls = (const float*)d_in[12];
    float* out = (float*)d_out;

    char* p = (char*)d_ws;
    auto alloc = [&](size_t bytes) { char* r = p; p += (bytes + 255) & ~(size_t)255; return r; };
    float*          h32   = (float*)alloc((size_t)NPAD * 128 * 4);
    unsigned short* h_hi  = (unsigned short*)alloc((size_t)NPAD * 128 * 2);
    unsigned short* h_lo  = (unsigned short*)alloc((size_t)NPAD * 128 * 2);
    unsigned short* a_hi  = (unsigned short*)alloc((size_t)NPAD * 128 * 2);
    unsigned short* WeH   = (unsigned short*)alloc((size_t)N_ETYPES * 16384 * 2);
    unsigned short* WihH  = (unsigned short*)alloc((size_t)16 * 384 * 8 * 2);
    unsigned short* WhhH  = (unsigned short*)alloc((size_t)16 * 384 * 8 * 2);
    int* cntDT    = (int*)alloc((size_t)NTS * 4);
    int* rowptrDT = (int*)alloc((size_t)(NTS + 1) * 4);
    int* cursorDT = (int*)alloc((size_t)NTS * 4);
    int* epay     = (int*)alloc((size_t)E_EDGES * 4);
    int* bsum     = (int*)alloc((size_t)NSB * 4);
    int* bofs     = (int*)alloc((size_t)NSB * 4);
    float* prebias = (float*)alloc((size_t)NPAD * 128 * 4);
    float* hg     = (float*)alloc((size_t)N_GRAPHS * HID * 4);

    // one-time prep
    const int IW_GRID = (NPAD * HID + N_ETYPES * 2048 + 2 * 16 * 384 + 255) / 256;
    k_initW<<<IW_GRID, 256, 0, stream>>>(feat, W_e, W_ih, W_hh, h32, h_hi, h_lo,
                                         WeH, WihH, WhhH);
    k_zeroi<<<(NTS + 255) / 256, 256, 0, stream>>>(cntDT, NTS);
    k_countDT<<<(E_EDGES + 255) / 256, 256, 0, stream>>>(dst, et, cntDT);
    k_su1<<<NSB, 512, 0, stream>>>(cntDT, bsum);
    k_su2<<<1, 512, 0, stream>>>(bsum, bofs);
    k_su3<<<NSB, 512, 0, stream>>>(cntDT, bofs, rowptrDT, cursorDT);
    k_fillDT<<<(E_EDGES + 255) / 256, 256, 0, stream>>>(src, dst, et, cursorDT, epay);
    k_prebias<<<(NPAD * HID + 255) / 256, 256, 0, stream>>>(rowptrDT, b_e, prebias);

    for (int step = 0; step < N_STEPS; ++step) {
        k_fuse<<<dim3(118, 2), 512, 0, stream>>>(
            h32, rowptrDT, epay, (const uint4*)WeH, prebias, a_hi);
        k_gru<<<NPAD / 16, 512, 0, stream>>>(
            a_hi, (const uint4*)WihH, (const uint4*)WhhH,
            b_ih, b_hh, h32, h_hi, h_lo);
    }

    k_zero<<<(N_GRAPHS * HID / 4 + 255) / 256, 256, 0, stream>>>(hg, N_GRAPHS * HID / 4);
    k_pool<<<(N_NODES * HID + 255) / 256, 256, 0, stream>>>(h32, gid, hg);
    k_cls<<<1, 640, 0, stream>>>(hg, W_cls, b_cls, out);
}

// Round 13
// 475.890 us; speedup vs baseline: 1.5400x; 1.5400x over previous
//
#include <hip/hip_runtime.h>
#include <math.h>

#define N_NODES 15000
#define NPAD    15104      // 118*128
#define E_EDGES 240000
#define IN_DIM  100
#define HID     128
#define N_ETYPES 13
#define N_STEPS  6
#define N_GRAPHS 64
#define N_CLASSES 10
#define NTS     (N_ETYPES * NPAD)   // 196352 (t,src) cells
#define NSB     384                 // scan blocks of 512

typedef short v8bf __attribute__((ext_vector_type(8)));
typedef float v4f  __attribute__((ext_vector_type(4)));

union FragU { uint4 u; v8bf b; };

static __device__ __forceinline__ float bf2f(unsigned short u) {
    union { unsigned int i; float f; } x; x.i = ((unsigned int)u) << 16; return x.f;
}
static __device__ __forceinline__ unsigned short f2bf(float f) {
    union { float f; unsigned int i; } x; x.f = f;
    unsigned int u = x.i;
    u = (u + 0x7fff + ((u >> 16) & 1)) >> 16;   // round-nearest-even
    return (unsigned short)u;
}
static __device__ __forceinline__ float sigm(float x) { return 1.f / (1.f + expf(-x)); }

// ---------------- merged one-time init: h planes + weight frag planes (hi only) ----------------
__global__ __launch_bounds__(256) void k_initW(
    const float* __restrict__ feat,
    const float* __restrict__ W_e, const float* __restrict__ W_ih, const float* __restrict__ W_hh,
    float* __restrict__ h32, unsigned short* __restrict__ h_hi, unsigned short* __restrict__ h_lo,
    unsigned short* __restrict__ WeH,
    unsigned short* __restrict__ WihH, unsigned short* __restrict__ WhhH)
{
    int idx = blockIdx.x * 256 + threadIdx.x;
    const int IH = NPAD * HID;
    const int NE = N_ETYPES * 2048;
    const int NG = 16 * 384;
    if (idx < IH) {
        int n = idx >> 7, c = idx & 127;
        float v = 0.f;
        if (n < N_NODES && c < IN_DIM) v = feat[n * IN_DIM + c];
        h32[idx] = v;
        unsigned short hi = f2bf(v);
        h_hi[idx] = hi;
        h_lo[idx] = f2bf(v - bf2f(hi));
        return;
    }
    int f = idx - IH;
    unsigned short th[8];
    if (f < NE) {
        int t = f >> 11, r = f & 2047, kcsub = r >> 7, c = r & 127;
        #pragma unroll
        for (int j = 0; j < 8; ++j)
            th[j] = f2bf(W_e[(long)t * 16384 + (kcsub * 8 + j) * 128 + c]);
        *(uint4*)(WeH + (long)t * 16384 + ((kcsub << 7) + c) * 8) = *(uint4*)th;
    } else if (f < NE + 2 * NG) {
        int f2 = f - NE;
        const float* srcp = (f2 < NG) ? W_ih : W_hh;
        unsigned short* dh = (f2 < NG) ? WihH : WhhH;
        int g = (f2 < NG) ? f2 : f2 - NG;
        int kcsub = g / 384, c = g - kcsub * 384;
        #pragma unroll
        for (int j = 0; j < 8; ++j)
            th[j] = f2bf(srcp[(long)c * 128 + kcsub * 8 + j]);   // B[k][c] = W[c][k]
        *(uint4*)(dh + ((long)kcsub * 384 + c) * 8) = *(uint4*)th;
    }
}

__global__ __launch_bounds__(256) void k_zero2(int* __restrict__ deg, int* __restrict__ used) {
    int idx = blockIdx.x * 256 + threadIdx.x;
    if (idx < NPAD) deg[idx] = 0;
    else if (idx < NPAD + NTS) used[idx - NPAD] = 0;
}

// ---------------- graph prep ----------------
__global__ __launch_bounds__(256) void k_count_mark(const int* __restrict__ src,
                                                    const int* __restrict__ dst,
                                                    const int* __restrict__ et,
                                                    int* __restrict__ deg,
                                                    int* __restrict__ used) {
    int e = blockIdx.x * 256 + threadIdx.x;
    if (e >= E_EDGES) return;
    atomicAdd(&deg[dst[e]], 1);
    used[et[e] * NPAD + src[e]] = 1;
}

__global__ __launch_bounds__(1024) void k_scan(const int* __restrict__ deg,
                                               int* __restrict__ rowptr, int* __restrict__ cursor) {
    __shared__ int part[1024];
    int tid = threadIdx.x;
    const int CH = 15;
    int base = tid * CH;
    int local[CH]; int s = 0;
    #pragma unroll
    for (int i = 0; i < CH; ++i) {
        int d = (base + i < NPAD) ? deg[base + i] : 0;
        local[i] = s; s += d;
    }
    part[tid] = s; __syncthreads();
    for (int off = 1; off < 1024; off <<= 1) {
        int v = (tid >= off) ? part[tid - off] : 0;
        __syncthreads();
        part[tid] += v;
        __syncthreads();
    }
    int excl = (tid > 0) ? part[tid - 1] : 0;
    #pragma unroll
    for (int i = 0; i < CH; ++i)
        if (base + i < NPAD) { rowptr[base + i] = excl + local[i]; cursor[base + i] = excl + local[i]; }
    if (tid == 0) rowptr[NPAD] = part[1023];
}

// ---- 3-phase scan over used[] -> slot[], rowlist[], tbase[] ----
__global__ __launch_bounds__(512) void k_su1(const int* __restrict__ used, int* __restrict__ bsum) {
    __shared__ int sh[512];
    int tid = threadIdx.x;
    int i = blockIdx.x * 512 + tid;
    sh[tid] = (i < NTS) ? used[i] : 0;
    __syncthreads();
    for (int off = 256; off > 0; off >>= 1) {
        if (tid < off) sh[tid] += sh[tid + off];
        __syncthreads();
    }
    if (tid == 0) bsum[blockIdx.x] = sh[0];
}

__global__ __launch_bounds__(512) void k_su2(const int* __restrict__ bsum, int* __restrict__ bofs) {
    __shared__ int sh[512];
    int tid = threadIdx.x;
    int v = (tid < NSB) ? bsum[tid] : 0;
    sh[tid] = v; __syncthreads();
    for (int off = 1; off < 512; off <<= 1) {
        int u = (tid >= off) ? sh[tid - off] : 0;
        __syncthreads();
        sh[tid] += u;
        __syncthreads();
    }
    if (tid < NSB) bofs[tid] = sh[tid] - v;   // exclusive
}

__global__ __launch_bounds__(512) void k_su3(const int* __restrict__ used,
                                             const int* __restrict__ bofs,
                                             int* __restrict__ slot,
                                             int* __restrict__ rowlist,
                                             int* __restrict__ tbase) {
    __shared__ int sh[512];
    int tid = threadIdx.x;
    int i = blockIdx.x * 512 + tid;
    int f = (i < NTS) ? used[i] : 0;
    sh[tid] = f; __syncthreads();
    for (int off = 1; off < 512; off <<= 1) {
        int u = (tid >= off) ? sh[tid - off] : 0;
        __syncthreads();
        sh[tid] += u;
        __syncthreads();
    }
    int g = bofs[blockIdx.x] + sh[tid] - f;   // global exclusive prefix
    if (i <= NTS) {
        if (i < NTS) slot[i] = g;
        int t = i / NPAD;
        if (i - t * NPAD == 0 || i == NTS) tbase[t] = g;   // i==NTS -> t==13
        if (f) rowlist[g] = i - t * NPAD;
    }
}

__global__ __launch_bounds__(256) void k_fill(const int* __restrict__ src, const int* __restrict__ dst,
                                              const int* __restrict__ et, const int* __restrict__ slot,
                                              int* __restrict__ cursor, int* __restrict__ eidx) {
    int e = blockIdx.x * 256 + threadIdx.x;
    if (e >= E_EDGES) return;
    int d = dst[e];
    int pos = atomicAdd(&cursor[d], 1);
    eidx[pos] = slot[et[e] * NPAD + src[e]];
}

// ---------------- etype GEMM (2-pass): Wh[gs] = h[rowlist[gs]] @ W_t + b_t ----------------
__global__ __launch_bounds__(512) void k_egemm(
    const unsigned short* __restrict__ Ahi, const unsigned short* __restrict__ Alo,
    const uint4* __restrict__ BH,
    const float* __restrict__ bias, const int* __restrict__ tbase,
    const int* __restrict__ rowlist, unsigned short* __restrict__ C)
{
    __shared__ uint4 blds[2048];             // 32 KB (B hi only)
    const int NW = 118 * N_ETYPES;           // 1534
    const int q = NW / 8, r8 = NW % 8;
    int bid = blockIdx.x;
    int xcd = bid & 7, ii = bid >> 3;
    int lid = (xcd < r8 ? xcd * (q + 1) : r8 * (q + 1) + (xcd - r8) * q) + ii;
    int rg = lid / N_ETYPES, t = lid - rg * N_ETYPES;

    int base = tbase[t], end = tbase[t + 1];
    if (rg * 128 >= end - base) return;

    int tid = threadIdx.x;
    {
        const uint4* bh = BH + t * 2048;
        #pragma unroll
        for (int it = 0; it < 4; ++it) {
            int f = it * 512 + tid;
            blds[f] = bh[f];
        }
    }
    __syncthreads();

    int lane = tid & 63, w = tid >> 6;
    int gs0 = base + rg * 128 + w * 16;
    int l15 = lane & 15, lsub = lane >> 4;

    int rowslot = gs0 + l15;
    int srcrow = (rowslot < end) ? rowlist[rowslot] : 0;

    FragU ah[4], al[4];
    const char* Ahb = (const char*)Ahi;
    const char* Alb = (const char*)Alo;
    #pragma unroll
    for (int kc = 0; kc < 4; ++kc) {
        long boff = (long)srcrow * 256 + kc * 64 + lsub * 16;
        ah[kc].u = *(const uint4*)(Ahb + boff);
        al[kc].u = *(const uint4*)(Alb + boff);
    }

    v4f acc[8];
    #pragma unroll
    for (int c8 = 0; c8 < 8; ++c8) acc[c8] = (v4f)(0.f);

    #pragma unroll
    for (int kc = 0; kc < 4; ++kc)
        #pragma unroll
        for (int c8 = 0; c8 < 8; ++c8) {
            int bi = (kc * 4 + lsub) * 128 + c8 * 16 + l15;
            FragU bhf; bhf.u = blds[bi];
            acc[c8] = __builtin_amdgcn_mfma_f32_16x16x32_bf16(ah[kc].b, bhf.b, acc[c8], 0, 0, 0);
            acc[c8] = __builtin_amdgcn_mfma_f32_16x16x32_bf16(al[kc].b, bhf.b, acc[c8], 0, 0, 0);
        }

    const float* bs = bias + t * 128;
    int gbase = gs0 + lsub * 4;              // C/D: col = lane&15, row = lsub*4 + i
    #pragma unroll
    for (int c8 = 0; c8 < 8; ++c8) {
        int col = c8 * 16 + l15;
        float bv = bs[col];
        #pragma unroll
        for (int i = 0; i < 4; ++i) {
            int gs2 = gbase + i;
            if (gs2 < end) C[(long)gs2 * 128 + col] = f2bf(acc[c8][i] + bv);
        }
    }
}

// ---------------- fused agg + GRU ----------------
// block = 16 dst rows, 512 thr = 8 waves.
// Phase 1: wave w aggregates rows 2w, 2w+1 (k_agg's 16B-gather + shfl pattern) -> LDS bf16 tile.
// Phase 2: GRU (GI 1-pass from LDS a-tile, GH 2-pass), h updated in place.
__global__ __launch_bounds__(512) void k_aggru(
    const int* __restrict__ rowptr, const int* __restrict__ eidx,
    const uint4* __restrict__ Wh,
    const uint4* __restrict__ WihH, const uint4* __restrict__ WhhH,
    const float* __restrict__ b_ih, const float* __restrict__ b_hh,
    float* __restrict__ h32,
    unsigned short* __restrict__ h_hi, unsigned short* __restrict__ h_lo)
{
    __shared__ char atile[16 * 256];          // 4 KB bf16 a-tile, XOR-swizzled
    int tid = threadIdx.x, lane = tid & 63, w = tid >> 6;
    int r0 = blockIdx.x * 16;

    // ---- phase 1: aggregate 2 rows per wave ----
    {
        int g = lane >> 4, c16 = lane & 15;
        #pragma unroll
        for (int rr = 0; rr < 2; ++rr) {
            int rloc = w * 2 + rr;
            int d = r0 + rloc;
            int s = rowptr[d], e = rowptr[d + 1];
            float acc[8] = {};
            for (int i = s + g; i < e; i += 4) {
                int slot = eidx[i];
                uint4 v = Wh[(long)slot * 16 + c16];
                unsigned int ua[4] = {v.x, v.y, v.z, v.w};
                #pragma unroll
                for (int q = 0; q < 4; ++q) {
                    acc[2 * q]     += bf2f((unsigned short)(ua[q] & 0xffff));
                    acc[2 * q + 1] += bf2f((unsigned short)(ua[q] >> 16));
                }
            }
            #pragma unroll
            for (int q = 0; q < 8; ++q) {
                acc[q] += __shfl_xor(acc[q], 16);
                acc[q] += __shfl_xor(acc[q], 32);
            }
            if (g == 0) {
                unsigned short hb[8];
                #pragma unroll
                for (int q = 0; q < 8; ++q) hb[q] = f2bf(acc[q]);
                int byt = (rloc * 256 + c16 * 16) ^ ((rloc & 7) << 4);
                *(uint4*)(atile + byt) = *(uint4*)hb;
            }
        }
    }

    // ---- phase 2: GRU ----
    int cg = w;                               // wave = col group
    int l15 = lane & 15, lsub = lane >> 4;

    FragU hh[2][4];
    {
        const char* hhb = (const char*)h_hi;
        const char* hlb = (const char*)h_lo;
        #pragma unroll
        for (int kc = 0; kc < 4; ++kc) {
            long boff = (long)(r0 + l15) * 256 + kc * 64 + lsub * 16;
            hh[0][kc].u = *(const uint4*)(hhb + boff);
            hh[1][kc].u = *(const uint4*)(hlb + boff);
        }
    }
    __syncthreads();   // a-tile complete; h rows loaded before in-place writes

    FragU aa[4];
    #pragma unroll
    for (int kc = 0; kc < 4; ++kc) {
        int byt = (l15 * 256 + kc * 64 + lsub * 16) ^ ((l15 & 7) << 4);
        aa[kc].u = *(const uint4*)(atile + byt);
    }

    v4f accI[3], accH[3];
    #pragma unroll
    for (int g = 0; g < 3; ++g) { accI[g] = (v4f)(0.f); accH[g] = (v4f)(0.f); }

    #pragma unroll
    for (int kc = 0; kc < 4; ++kc)
        #pragma unroll
        for (int g = 0; g < 3; ++g) {
            int bi = (kc * 4 + lsub) * 384 + g * 128 + cg * 16 + l15;
            FragU wih, whh;
            wih.u = WihH[bi]; whh.u = WhhH[bi];
            accI[g] = __builtin_amdgcn_mfma_f32_16x16x32_bf16(aa[kc].b,    wih.b, accI[g], 0, 0, 0);
            accH[g] = __builtin_amdgcn_mfma_f32_16x16x32_bf16(hh[0][kc].b, whh.b, accH[g], 0, 0, 0);
            accH[g] = __builtin_amdgcn_mfma_f32_16x16x32_bf16(hh[1][kc].b, whh.b, accH[g], 0, 0, 0);
        }

    int c = cg * 16 + l15;
    float bir = b_ih[c], biz = b_ih[c + 128], bin = b_ih[c + 256];
    float bhr = b_hh[c], bhz = b_hh[c + 128], bhn = b_hh[c + 256];
    #pragma unroll
    for (int i = 0; i < 4; ++i) {
        int row = r0 + lsub * 4 + i;
        float ir = accI[0][i] + bir, iz = accI[1][i] + biz, inn = accI[2][i] + bin;
        float hr = accH[0][i] + bhr, hz = accH[1][i] + bhz, hn = accH[2][i] + bhn;
        float rr = sigm(ir + hr);
        float zg = sigm(iz + hz);
        float ng = tanhf(inn + rr * hn);
        long off = (long)row * 128 + c;
        float ho = h32[off];
        float hv = (1.f - zg) * ng + zg * ho;
        if (row < N_NODES) {
            h32[off] = hv;
            unsigned short hi_ = f2bf(hv);
            h_hi[off] = hi_;
            h_lo[off] = f2bf(hv - bf2f(hi_));
        }
    }
}

// ---------------- pooling + classifier ----------------
__global__ __launch_bounds__(256) void k_pool(const float* __restrict__ h32,
                                              const int* __restrict__ gid,
                                              float* __restrict__ hg) {
    int idx = blockIdx.x * 256 + threadIdx.x;
    if (idx >= N_NODES * HID) return;
    int n = idx >> 7, c = idx & 127;
    atomicAdd(&hg[gid[n] * HID + c], h32[idx]);
}

__global__ __launch_bounds__(256) void k_zero(float* __restrict__ p, long n4) {
    long i = (long)blockIdx.x * 256 + threadIdx.x;
    if (i < n4) ((float4*)p)[i] = make_float4(0.f, 0.f, 0.f, 0.f);
}

__global__ __launch_bounds__(640) void k_cls(const float* __restrict__ hg,
                                             const float* __restrict__ Wc,
                                             const float* __restrict__ bc,
                                             float* __restrict__ out) {
    int tid = threadIdx.x;
    if (tid >= N_GRAPHS * N_CLASSES) return;
    int g = tid / N_CLASSES, c = tid - g * N_CLASSES;
    float s = bc[c];
    for (int k = 0; k < HID; ++k) s = fmaf(hg[g * HID + k], Wc[c * HID + k], s);
    out[tid] = s;
}

// ---------------- launch ----------------
extern "C" void kernel_launch(void* const* d_in, const int* in_sizes, int n_in,
                              void* d_out, int out_size, void* d_ws, size_t ws_size,
                              hipStream_t stream) {
    const float* feat  = (const float*)d_in[0];
    const int*   src   = (const int*)d_in[1];
    const int*   dst   = (const int*)d_in[2];
    const int*   et    = (const int*)d_in[3];
    const int*   gid   = (const int*)d_in[4];
    const float* W_e   = (const float*)d_in[5];
    const float* b_e   = (const float*)d_in[6];
    const float* W_ih  = (const float*)d_in[7];
    const float* W_hh  = (const float*)d_in[8];
    const float* b_ih  = (const float*)d_in[9];
    const float* b_hh  = (const float*)d_in[10];
    const float* W_cls = (const float*)d_in[11];
    const float* b_cls = (const float*)d_in[12];
    float* out = (float*)d_out;

    char* p = (char*)d_ws;
    auto alloc = [&](size_t bytes) { char* r = p; p += (bytes + 255) & ~(size_t)255; return r; };
    float*          h32  = (float*)alloc((size_t)NPAD * 128 * 4);
    unsigned short* h_hi = (unsigned short*)alloc((size_t)NPAD * 128 * 2);
    unsigned short* h_lo = (unsigned short*)alloc((size_t)NPAD * 128 * 2);
    unsigned short* Wh   = (unsigned short*)alloc((size_t)NTS * 128 * 2);
    unsigned short* WeH  = (unsigned short*)alloc((size_t)N_ETYPES * 16384 * 2);
    unsigned short* WihH = (unsigned short*)alloc((size_t)16 * 384 * 8 * 2);
    unsigned short* WhhH = (unsigned short*)alloc((size_t)16 * 384 * 8 * 2);
    int* deg     = (int*)alloc((size_t)NPAD * 4);
    int* rowptr  = (int*)alloc((size_t)(NPAD + 1) * 4);
    int* cursor  = (int*)alloc((size_t)NPAD * 4);
    int* eidx    = (int*)alloc((size_t)E_EDGES * 4);
    int* used    = (int*)alloc((size_t)NTS * 4);
    int* slot    = (int*)alloc((size_t)NTS * 4);
    int* rowlist = (int*)alloc((size_t)NTS * 4);
    int* bsum    = (int*)alloc((size_t)NSB * 4);
    int* bofs    = (int*)alloc((size_t)NSB * 4);
    int* tbase   = (int*)alloc((size_t)(N_ETYPES + 1) * 4);
    float* hg    = (float*)alloc((size_t)N_GRAPHS * HID * 4);

    // one-time prep
    const int IW_GRID = (NPAD * HID + N_ETYPES * 2048 + 2 * 16 * 384 + 255) / 256;
    k_initW<<<IW_GRID, 256, 0, stream>>>(feat, W_e, W_ih, W_hh, h32, h_hi, h_lo,
                                         WeH, WihH, WhhH);
    k_zero2<<<(NPAD + NTS + 255) / 256, 256, 0, stream>>>(deg, used);
    k_count_mark<<<(E_EDGES + 255) / 256, 256, 0, stream>>>(src, dst, et, deg, used);
    k_scan<<<1, 1024, 0, stream>>>(deg, rowptr, cursor);
    k_su1<<<NSB, 512, 0, stream>>>(used, bsum);
    k_su2<<<1, 512, 0, stream>>>(bsum, bofs);
    k_su3<<<NSB, 512, 0, stream>>>(used, bofs, slot, rowlist, tbase);
    k_fill<<<(E_EDGES + 255) / 256, 256, 0, stream>>>(src, dst, et, slot, cursor, eidx);

    for (int step = 0; step < N_STEPS; ++step) {
        k_egemm<<<118 * N_ETYPES, 512, 0, stream>>>(
            h_hi, h_lo, (const uint4*)WeH, b_e, tbase, rowlist, Wh);
        k_aggru<<<NPAD / 16, 512, 0, stream>>>(
            rowptr, eidx, (const uint4*)Wh,
            (const uint4*)WihH, (const uint4*)WhhH,
            b_ih, b_hh, h32, h_hi, h_lo);
    }

    k_zero<<<(N_GRAPHS * HID / 4 + 255) / 256, 256, 0, stream>>>(hg, N_GRAPHS * HID / 4);
    k_pool<<<(N_NODES * HID + 255) / 256, 256, 0, stream>>>(h32, gid, hg);
    k_cls<<<1, 640, 0, stream>>>(hg, W_cls, b_cls, out);
}